// Round 2
// baseline (2379.243 us; speedup 1.0000x reference)
//
#include <hip/hip_runtime.h>

#define BS   4096   // BATCH*SEQ
#define SEQL 2048
#define DM   1024
#define DH   4096
#define NV   32000

using u16 = unsigned short;

typedef __attribute__((ext_vector_type(8))) short bf16x8;
typedef __attribute__((ext_vector_type(4))) float f32x4;

__device__ __forceinline__ u16 f2b(float f) {
  union { float f; unsigned u; } c; c.f = f;
  unsigned u = c.u;
  u = (u + 0x7FFFu + ((u >> 16) & 1u)) >> 16;
  return (u16)u;
}

__device__ __forceinline__ void gld16(const u16* g, u16* l) {
  __builtin_amdgcn_global_load_lds(
      (__attribute__((address_space(1))) void*)(void*)const_cast<u16*>(g),
      (__attribute__((address_space(3))) void*)l, 16, 0, 0);
}

// ---------------- embed: x[row,:] = emb[tok[row],:] ----------------
__global__ __launch_bounds__(256) void k_embed(const int* __restrict__ tok,
                                               const float* __restrict__ emb,
                                               float* __restrict__ x) {
  const long row = blockIdx.x;
  const long e = tok[row];
  ((float4*)(x + row * DM))[threadIdx.x] = ((const float4*)(emb + e * DM))[threadIdx.x];
}

// ---------------- f32 -> bf16 convert (n4 = count of float4) ----------------
__global__ __launch_bounds__(256) void k_cvt(const float* __restrict__ in,
                                             u16* __restrict__ out, int n4) {
  int i = blockIdx.x * 256 + threadIdx.x;
  if (i < n4) {
    float4 v = ((const float4*)in)[i];
    ushort4 o;
    o.x = f2b(v.x); o.y = f2b(v.y); o.z = f2b(v.z); o.w = f2b(v.w);
    ((ushort4*)out)[i] = o;
  }
}

// ---------------- LayerNorm row kernel: f32 in -> bf16 out ----------------
__global__ __launch_bounds__(256) void k_ln(const float* __restrict__ x,
                                            const float* __restrict__ g,
                                            const float* __restrict__ b,
                                            u16* __restrict__ out) {
  const long row = blockIdx.x;
  const int t = threadIdx.x;
  float4 v = ((const float4*)(x + row * DM))[t];
  float s  = v.x + v.y + v.z + v.w;
  float q2 = v.x*v.x + v.y*v.y + v.z*v.z + v.w*v.w;
#pragma unroll
  for (int o = 1; o < 64; o <<= 1) { s += __shfl_xor(s, o); q2 += __shfl_xor(q2, o); }
  __shared__ float rs_[4], rq_[4];
  const int lane = t & 63, wid = t >> 6;
  if (lane == 0) { rs_[wid] = s; rq_[wid] = q2; }
  __syncthreads();
  s  = rs_[0] + rs_[1] + rs_[2] + rs_[3];
  q2 = rq_[0] + rq_[1] + rq_[2] + rq_[3];
  const float mu   = s * (1.f / 1024.f);
  const float var  = q2 * (1.f / 1024.f) - mu * mu;
  const float rstd = rsqrtf(var + 1e-5f);
  float4 gg = ((const float4*)g)[t];
  float4 bb = ((const float4*)b)[t];
  ushort4 o;
  o.x = f2b((v.x - mu) * rstd * gg.x + bb.x);
  o.y = f2b((v.y - mu) * rstd * gg.y + bb.y);
  o.z = f2b((v.z - mu) * rstd * gg.z + bb.z);
  o.w = f2b((v.w - mu) * rstd * gg.w + bb.w);
  ((ushort4*)(out + row * DM))[t] = o;
}

// ---------------- 32x32 tiled transpose, optional f32->bf16 ----------------
__device__ __forceinline__ u16 to_b16(float v) { return f2b(v); }
__device__ __forceinline__ u16 to_b16(u16 v)   { return v; }

template <typename T>
__global__ __launch_bounds__(256) void k_transpose(const T* __restrict__ in,
                                                   u16* __restrict__ out,
                                                   int R, int C, long inz, long outz) {
  __shared__ u16 tile[32][33];
  const T* ip = in + (long)blockIdx.z * inz;
  u16* op = out + (long)blockIdx.z * outz;
  const int tx = threadIdx.x & 31, ty = threadIdx.x >> 5;
  const long c0 = (long)blockIdx.x * 32, r0 = (long)blockIdx.y * 32;
#pragma unroll
  for (int i = 0; i < 4; ++i)
    tile[ty + i * 8][tx] = to_b16(ip[(r0 + ty + i * 8) * C + c0 + tx]);
  __syncthreads();
#pragma unroll
  for (int i = 0; i < 4; ++i)
    op[(c0 + ty + i * 8) * R + r0 + tx] = tile[tx][ty + i * 8];
}

// ---------------- causal row softmax: f32 scores -> bf16 attn ----------------
__global__ __launch_bounds__(256) void k_softmax(const float* __restrict__ sc,
                                                 u16* __restrict__ at) {
  const int r = blockIdx.x;
  const long z = blockIdx.y;
  const int t = threadIdx.x;
  const float* row = sc + (z * SEQL + r) * SEQL;
  u16* orow = at + (z * SEQL + r) * SEQL;
  float vals[8];
  float mx = -3.4e38f;
#pragma unroll
  for (int i = 0; i < 8; ++i) {
    int c = i * 256 + t;
    float v = (c <= r) ? row[c] : -3.4e38f;
    vals[i] = v;
    mx = fmaxf(mx, v);
  }
#pragma unroll
  for (int o = 1; o < 64; o <<= 1) mx = fmaxf(mx, __shfl_xor(mx, o));
  __shared__ float rm[4], rsum[4];
  const int lane = t & 63, wid = t >> 6;
  if (lane == 0) rm[wid] = mx;
  __syncthreads();
  mx = fmaxf(fmaxf(rm[0], rm[1]), fmaxf(rm[2], rm[3]));
  float sum = 0.f;
#pragma unroll
  for (int i = 0; i < 8; ++i) {
    int c = i * 256 + t;
    float e = (c <= r) ? __expf(vals[i] - mx) : 0.f;
    vals[i] = e;
    sum += e;
  }
#pragma unroll
  for (int o = 1; o < 64; o <<= 1) sum += __shfl_xor(sum, o);
  if (lane == 0) rsum[wid] = sum;
  __syncthreads();
  sum = rsum[0] + rsum[1] + rsum[2] + rsum[3];
  const float inv = 1.f / sum;
#pragma unroll
  for (int i = 0; i < 8; ++i) orow[i * 256 + t] = f2b(vals[i] * inv);
}

// ---------------- bf16 GEMM: C[M,N] = A[M,K] @ B[N,K]^T (B^T layout) -------
// EPI: 0 = f32 store (with scale), 1 = bf16 store, 2 = f32 +=
// CAUSAL: 0 = none, 1 = skip blocks with col0 > row0+127 (scores),
//         2 = K-loop limited to row0+128 (A rows are causal-zero beyond)
// SWZ: XCD-aware block swizzle (grid size must be divisible by 8)
template <int EPI, bool BIAS, bool LRELU, int CAUSAL, bool SWZ>
__global__ __launch_bounds__(256, 2) void k_gemm_bt(
    const u16* __restrict__ A, const u16* __restrict__ B, void* __restrict__ C,
    const float* __restrict__ bias, int K, int N,
    long sAz, long sBz, long sCz, float scale) {
  __shared__ u16 lA[128 * 32];
  __shared__ u16 lB[128 * 32];
  const int t = threadIdx.x;
  const long z = blockIdx.z;
  int bx = blockIdx.x, by = blockIdx.y;
  if (SWZ) {
    int id = bx + gridDim.x * by;
    int cpx = (gridDim.x * gridDim.y) >> 3;
    int s = (id & 7) * cpx + (id >> 3);
    bx = s % gridDim.x;
    by = s / gridDim.x;
  }
  const long row0 = (long)bx * 128;
  const long col0 = (long)by * 128;
  if (CAUSAL == 1 && col0 > row0 + 127) return;
  const int Klim = (CAUSAL == 2) ? min(K, (int)row0 + 128) : K;
  const u16* Ab = A + z * sAz;
  const u16* Bb = B + z * sBz;

  const int rr = t >> 2;           // 0..63
  const int c8 = (t & 3) * 8;      // 0,8,16,24
  const u16* gA0 = Ab + (row0 + rr) * K + c8;
  const u16* gA1 = Ab + (row0 + 64 + rr) * K + c8;
  const u16* gB0 = Bb + (col0 + rr) * K + c8;
  const u16* gB1 = Bb + (col0 + 64 + rr) * K + c8;
  u16* sA0 = &lA[rr * 32 + c8];
  u16* sA1 = &lA[(64 + rr) * 32 + c8];
  u16* sB0 = &lB[rr * 32 + c8];
  u16* sB1 = &lB[(64 + rr) * 32 + c8];

  const int lane = t & 63;
  const int w = t >> 6;
  const int wr = (w >> 1) * 64, wc = (w & 1) * 64;
  const int fr = lane & 15;
  const int fk = (lane >> 4) * 8;

  f32x4 acc[4][4] = {};

  for (int k0 = 0; k0 < Klim; k0 += 32) {
    gld16(gA0 + k0, sA0);
    gld16(gA1 + k0, sA1);
    gld16(gB0 + k0, sB0);
    gld16(gB1 + k0, sB1);
    __syncthreads();
    bf16x8 av[4], bv[4];
#pragma unroll
    for (int m = 0; m < 4; ++m) av[m] = *(const bf16x8*)&lA[(wr + m * 16 + fr) * 32 + fk];
#pragma unroll
    for (int n = 0; n < 4; ++n) bv[n] = *(const bf16x8*)&lB[(wc + n * 16 + fr) * 32 + fk];
#pragma unroll
    for (int m = 0; m < 4; ++m)
#pragma unroll
      for (int n = 0; n < 4; ++n)
        acc[m][n] = __builtin_amdgcn_mfma_f32_16x16x32_bf16(av[m], bv[n], acc[m][n], 0, 0, 0);
    __syncthreads();
  }

  const int er = (lane >> 4) * 4;
  const int ec = lane & 15;
#pragma unroll
  for (int m = 0; m < 4; ++m) {
#pragma unroll
    for (int n = 0; n < 4; ++n) {
#pragma unroll
      for (int j = 0; j < 4; ++j) {
        long r = row0 + wr + m * 16 + er + j;
        long c = col0 + wc + n * 16 + ec;
        float v = acc[m][n][j] * scale;
        if (BIAS)  v += bias[c];
        if (LRELU) v = v > 0.f ? v : 0.01f * v;
        if (EPI == 0)      ((float*)C)[z * sCz + r * (long)N + c] = v;
        else if (EPI == 1) ((u16*)C)[z * sCz + r * (long)N + c] = f2b(v);
        else               ((float*)C)[z * sCz + r * (long)N + c] += v;
      }
    }
  }
}

extern "C" void kernel_launch(void* const* d_in, const int* in_sizes, int n_in,
                              void* d_out, int out_size, void* d_ws, size_t ws_size,
                              hipStream_t stream) {
  const int*   tokens = (const int*)d_in[0];
  const float* emb    = (const float*)d_in[1];
  const float* qk     = (const float*)d_in[2];
  const float* ov     = (const float*)d_in[3];
  const float* wup    = (const float*)d_in[4];
  const float* bup    = (const float*)d_in[5];
  const float* whid   = (const float*)d_in[6];
  const float* bhid   = (const float*)d_in[7];
  const float* wdown  = (const float*)d_in[8];
  const float* bdown  = (const float*)d_in[9];
  const float* g1     = (const float*)d_in[10];
  const float* b1     = (const float*)d_in[11];
  const float* g2     = (const float*)d_in[12];
  const float* b2     = (const float*)d_in[13];

  // scratch carved out of d_out (524 MB; only written by the final GEMM)
  char* Ob = (char*)d_out;
  float* scores = (float*)(Ob + 0);              // 33554432 B
  u16*   attn   = (u16*)(Ob + 33554432);         // 16777216 B
  u16*   m1     = (u16*)(Ob + 50331648);         // 33554432 B
  u16*   m2     = (u16*)(Ob + 83886080);         // 33554432 B
  u16*   qkT    = (u16*)(Ob + 117440512);        // 4 layers [1024][1024] bf16
  u16*   ovT    = (u16*)(Ob + 125829120);        // 4 layers
  u16*   upT    = (u16*)(Ob + 134217728);        // 4 layers [4096][1024]
  u16*   hidT   = (u16*)(Ob + 167772160);        // 4 layers [4096][4096]
  u16*   downT  = (u16*)(Ob + 301989888);        // 4 layers [1024][4096]
  float* xres   = (float*)(Ob + 335544320);      // residual f32 [4096][1024]
  u16*   h      = (u16*)(Ob + 352321536);        // LN out bf16
  u16*   hT     = (u16*)(Ob + 360710144);        // [2][1024][2048]
  u16*   q      = (u16*)(Ob + 369098752);        // [4096][1024]
  u16*   attnV  = (u16*)(Ob + 377487360);        // [4096][1024]

  // buffers live during the final GEMM go in d_ws
  u16* embB = (u16*)d_ws;                        // [32000][1024] bf16
  u16* xB   = (u16*)((char*)d_ws + 65536000);    // [4096][1024] bf16

  k_embed<<<dim3(BS), 256, 0, stream>>>(tokens, emb, xres);
  k_cvt<<<dim3(32000), 256, 0, stream>>>(emb, embB, 8192000);

  // all-layer batched weight transposes (z = layer)
  k_transpose<float><<<dim3(32, 32, 4),   256, 0, stream>>>(qk,    qkT,   1024, 1024, 1048576,  1048576);
  k_transpose<float><<<dim3(32, 32, 4),   256, 0, stream>>>(ov,    ovT,   1024, 1024, 1048576,  1048576);
  k_transpose<float><<<dim3(128, 32, 4),  256, 0, stream>>>(wup,   upT,   1024, 4096, 4194304,  4194304);
  k_transpose<float><<<dim3(128, 128, 4), 256, 0, stream>>>(whid,  hidT,  4096, 4096, 16777216, 16777216);
  k_transpose<float><<<dim3(32, 128, 4),  256, 0, stream>>>(wdown, downT, 4096, 1024, 4194304,  4194304);

  for (int l = 0; l < 4; ++l) {
    // ---- attention ----
    k_ln<<<dim3(BS), 256, 0, stream>>>(xres, g1 + l * 1024, b1 + l * 1024, h);
    k_transpose<u16><<<dim3(32, 64, 2), 256, 0, stream>>>(h, hT, 2048, 1024, 2048L * 1024, 1024L * 2048);
    // q = (h @ qk) / sqrt(d)
    k_gemm_bt<1, false, false, 0, false><<<dim3(32, 8, 1), 256, 0, stream>>>(
        h, qkT + (long)l * 1048576, q, nullptr, 1024, 1024, 0, 0, 0, 0.03125f);
    // scores[z] = q[z] @ h[z]^T  (skip upper-triangle blocks)
    k_gemm_bt<0, false, false, 1, false><<<dim3(16, 16, 2), 256, 0, stream>>>(
        q, h, scores, nullptr, 1024, 2048, 2048L * 1024, 2048L * 1024, 2048L * 2048, 1.f);
    k_softmax<<<dim3(2048, 2), 256, 0, stream>>>(scores, attn);
    // attnV[z] = attn[z] @ h[z]  (K-loop limited by causal zero structure)
    k_gemm_bt<1, false, false, 2, false><<<dim3(16, 8, 2), 256, 0, stream>>>(
        attn, hT, attnV, nullptr, 2048, 1024, 2048L * 2048, 1024L * 2048, 2048L * 1024, 1.f);
    // x += attnV @ ov
    k_gemm_bt<2, false, false, 0, false><<<dim3(32, 8, 1), 256, 0, stream>>>(
        attnV, ovT + (long)l * 1048576, xres, nullptr, 1024, 1024, 0, 0, 0, 1.f);

    // ---- MLP ----
    k_ln<<<dim3(BS), 256, 0, stream>>>(xres, g2 + l * 1024, b2 + l * 1024, h);
    k_gemm_bt<1, true, true, 0, false><<<dim3(32, 32, 1), 256, 0, stream>>>(
        h, upT + (long)l * 4194304, m1, bup + l * 4096, 1024, 4096, 0, 0, 0, 1.f);
    k_gemm_bt<1, true, true, 0, false><<<dim3(32, 32, 1), 256, 0, stream>>>(
        m1, hidT + (long)l * 16777216, m2, bhid + l * 4096, 4096, 4096, 0, 0, 0, 1.f);
    k_gemm_bt<2, true, true, 0, false><<<dim3(32, 8, 1), 256, 0, stream>>>(
        m2, downT + (long)l * 4194304, xres, bdown + l * 1024, 4096, 1024, 0, 0, 0, 1.f);
  }

  // ---- logits = x @ emb^T  (XCD-swizzled: 8000 blocks % 8 == 0) ----
  k_cvt<<<dim3(4096), 256, 0, stream>>>(xres, xB, 1048576);
  k_gemm_bt<0, false, false, 0, true><<<dim3(32, 250, 1), 256, 0, stream>>>(
      xB, embB, (float*)d_out, nullptr, 1024, 32000, 0, 0, 0, 1.f);
}

// Round 3
// 2139.838 us; speedup vs baseline: 1.1119x; 1.1119x over previous
//
#include <hip/hip_runtime.h>

#define BS   4096   // BATCH*SEQ
#define SEQL 2048
#define DM   1024
#define DH   4096
#define NV   32000

using u16 = unsigned short;

typedef __attribute__((ext_vector_type(8))) short bf16x8;
typedef __attribute__((ext_vector_type(4))) float f32x4;

__device__ __forceinline__ u16 f2b(float f) {
  union { float f; unsigned u; } c; c.f = f;
  unsigned u = c.u;
  u = (u + 0x7FFFu + ((u >> 16) & 1u)) >> 16;
  return (u16)u;
}

__device__ __forceinline__ void gld16(const u16* g, u16* l) {
  __builtin_amdgcn_global_load_lds(
      (__attribute__((address_space(1))) void*)(void*)const_cast<u16*>(g),
      (__attribute__((address_space(3))) void*)l, 16, 0, 0);
}

// ---------------- embed ----------------
__global__ __launch_bounds__(256) void k_embed(const int* __restrict__ tok,
                                               const float* __restrict__ emb,
                                               float* __restrict__ x) {
  const long row = blockIdx.x;
  const long e = tok[row];
  ((float4*)(x + row * DM))[threadIdx.x] = ((const float4*)(emb + e * DM))[threadIdx.x];
}

// ---------------- f32 -> bf16 convert ----------------
__global__ __launch_bounds__(256) void k_cvt(const float* __restrict__ in,
                                             u16* __restrict__ out, int n4) {
  int i = blockIdx.x * 256 + threadIdx.x;
  if (i < n4) {
    float4 v = ((const float4*)in)[i];
    ushort4 o;
    o.x = f2b(v.x); o.y = f2b(v.y); o.z = f2b(v.z); o.w = f2b(v.w);
    ((ushort4*)out)[i] = o;
  }
}

// ---------------- LayerNorm ----------------
__global__ __launch_bounds__(256) void k_ln(const float* __restrict__ x,
                                            const float* __restrict__ g,
                                            const float* __restrict__ b,
                                            u16* __restrict__ out) {
  const long row = blockIdx.x;
  const int t = threadIdx.x;
  float4 v = ((const float4*)(x + row * DM))[t];
  float s  = v.x + v.y + v.z + v.w;
  float q2 = v.x*v.x + v.y*v.y + v.z*v.z + v.w*v.w;
#pragma unroll
  for (int o = 1; o < 64; o <<= 1) { s += __shfl_xor(s, o); q2 += __shfl_xor(q2, o); }
  __shared__ float rs_[4], rq_[4];
  const int lane = t & 63, wid = t >> 6;
  if (lane == 0) { rs_[wid] = s; rq_[wid] = q2; }
  __syncthreads();
  s  = rs_[0] + rs_[1] + rs_[2] + rs_[3];
  q2 = rq_[0] + rq_[1] + rq_[2] + rq_[3];
  const float mu   = s * (1.f / 1024.f);
  const float var  = q2 * (1.f / 1024.f) - mu * mu;
  const float rstd = rsqrtf(var + 1e-5f);
  float4 gg = ((const float4*)g)[t];
  float4 bb = ((const float4*)b)[t];
  ushort4 o;
  o.x = f2b((v.x - mu) * rstd * gg.x + bb.x);
  o.y = f2b((v.y - mu) * rstd * gg.y + bb.y);
  o.z = f2b((v.z - mu) * rstd * gg.z + bb.z);
  o.w = f2b((v.w - mu) * rstd * gg.w + bb.w);
  ((ushort4*)(out + row * DM))[t] = o;
}

// ---------------- 32x32 tiled transpose ----------------
__device__ __forceinline__ u16 to_b16(float v) { return f2b(v); }
__device__ __forceinline__ u16 to_b16(u16 v)   { return v; }

template <typename T>
__global__ __launch_bounds__(256) void k_transpose(const T* __restrict__ in,
                                                   u16* __restrict__ out,
                                                   int R, int C, long inz, long outz) {
  __shared__ u16 tile[32][33];
  const T* ip = in + (long)blockIdx.z * inz;
  u16* op = out + (long)blockIdx.z * outz;
  const int tx = threadIdx.x & 31, ty = threadIdx.x >> 5;
  const long c0 = (long)blockIdx.x * 32, r0 = (long)blockIdx.y * 32;
#pragma unroll
  for (int i = 0; i < 4; ++i)
    tile[ty + i * 8][tx] = to_b16(ip[(r0 + ty + i * 8) * C + c0 + tx]);
  __syncthreads();
#pragma unroll
  for (int i = 0; i < 4; ++i)
    op[(c0 + ty + i * 8) * R + r0 + tx] = tile[tx][ty + i * 8];
}

// ---------------- causal row softmax ----------------
__global__ __launch_bounds__(256) void k_softmax(const float* __restrict__ sc,
                                                 u16* __restrict__ at) {
  const int r = blockIdx.x;
  const long z = blockIdx.y;
  const int t = threadIdx.x;
  const float* row = sc + (z * SEQL + r) * SEQL;
  u16* orow = at + (z * SEQL + r) * SEQL;
  float vals[8];
  float mx = -3.4e38f;
#pragma unroll
  for (int i = 0; i < 8; ++i) {
    int c = i * 256 + t;
    float v = (c <= r) ? row[c] : -3.4e38f;
    vals[i] = v;
    mx = fmaxf(mx, v);
  }
#pragma unroll
  for (int o = 1; o < 64; o <<= 1) mx = fmaxf(mx, __shfl_xor(mx, o));
  __shared__ float rm[4], rsum[4];
  const int lane = t & 63, wid = t >> 6;
  if (lane == 0) rm[wid] = mx;
  __syncthreads();
  mx = fmaxf(fmaxf(rm[0], rm[1]), fmaxf(rm[2], rm[3]));
  float sum = 0.f;
#pragma unroll
  for (int i = 0; i < 8; ++i) {
    int c = i * 256 + t;
    float e = (c <= r) ? __expf(vals[i] - mx) : 0.f;
    vals[i] = e;
    sum += e;
  }
#pragma unroll
  for (int o = 1; o < 64; o <<= 1) sum += __shfl_xor(sum, o);
  if (lane == 0) rsum[wid] = sum;
  __syncthreads();
  sum = rsum[0] + rsum[1] + rsum[2] + rsum[3];
  const float inv = 1.f / sum;
#pragma unroll
  for (int i = 0; i < 8; ++i) orow[i * 256 + t] = f2b(vals[i] * inv);
}

// ---------------- 128x128 bf16 GEMM (small/causal shapes) ----------------
// EPI: 0 = f32 store, 1 = bf16 store, 2 = f32 +=
// CAUSAL: 0 none, 1 skip upper blocks (scores), 2 K-limit (attnV)
template <int EPI, bool BIAS, bool LRELU, int CAUSAL>
__global__ __launch_bounds__(256, 2) void k_gemm_bt(
    const u16* __restrict__ A, const u16* __restrict__ B, void* __restrict__ C,
    const float* __restrict__ bias, int K, int N,
    long sAz, long sBz, long sCz, float scale) {
  __shared__ u16 lA[128 * 32];
  __shared__ u16 lB[128 * 32];
  const int t = threadIdx.x;
  const long z = blockIdx.z;
  const long row0 = (long)blockIdx.x * 128;
  const long col0 = (long)blockIdx.y * 128;
  if (CAUSAL == 1 && col0 > row0 + 127) return;
  const int Klim = (CAUSAL == 2) ? min(K, (int)row0 + 128) : K;
  const u16* Ab = A + z * sAz;
  const u16* Bb = B + z * sBz;

  const int rr = t >> 2;
  const int c8 = (t & 3) * 8;
  const u16* gA0 = Ab + (row0 + rr) * K + c8;
  const u16* gA1 = Ab + (row0 + 64 + rr) * K + c8;
  const u16* gB0 = Bb + (col0 + rr) * K + c8;
  const u16* gB1 = Bb + (col0 + 64 + rr) * K + c8;
  u16* sA0 = &lA[rr * 32 + c8];
  u16* sA1 = &lA[(64 + rr) * 32 + c8];
  u16* sB0 = &lB[rr * 32 + c8];
  u16* sB1 = &lB[(64 + rr) * 32 + c8];

  const int lane = t & 63;
  const int w = t >> 6;
  const int wr = (w >> 1) * 64, wc = (w & 1) * 64;
  const int fr = lane & 15;
  const int fk = (lane >> 4) * 8;

  f32x4 acc[4][4] = {};

  for (int k0 = 0; k0 < Klim; k0 += 32) {
    gld16(gA0 + k0, sA0);
    gld16(gA1 + k0, sA1);
    gld16(gB0 + k0, sB0);
    gld16(gB1 + k0, sB1);
    __syncthreads();
    bf16x8 av[4], bv[4];
#pragma unroll
    for (int m = 0; m < 4; ++m) av[m] = *(const bf16x8*)&lA[(wr + m * 16 + fr) * 32 + fk];
#pragma unroll
    for (int n = 0; n < 4; ++n) bv[n] = *(const bf16x8*)&lB[(wc + n * 16 + fr) * 32 + fk];
#pragma unroll
    for (int m = 0; m < 4; ++m)
#pragma unroll
      for (int n = 0; n < 4; ++n)
        acc[m][n] = __builtin_amdgcn_mfma_f32_16x16x32_bf16(av[m], bv[n], acc[m][n], 0, 0, 0);
    __syncthreads();
  }

  const int er = (lane >> 4) * 4;
  const int ec = lane & 15;
#pragma unroll
  for (int m = 0; m < 4; ++m) {
#pragma unroll
    for (int n = 0; n < 4; ++n) {
#pragma unroll
      for (int j = 0; j < 4; ++j) {
        long r = row0 + wr + m * 16 + er + j;
        long c = col0 + wc + n * 16 + ec;
        float v = acc[m][n][j] * scale;
        if (BIAS)  v += bias[c];
        if (LRELU) v = v > 0.f ? v : 0.01f * v;
        if (EPI == 0)      ((float*)C)[z * sCz + r * (long)N + c] = v;
        else if (EPI == 1) ((u16*)C)[z * sCz + r * (long)N + c] = f2b(v);
        else               ((float*)C)[z * sCz + r * (long)N + c] += v;
      }
    }
  }
}

// ---------------- 256x256 BK=64 8-wave bf16 GEMM (large shapes) ----------------
// C[M,N] = A[M,K] @ B[N,K]^T.  Double-buffered 128KB LDS, st_16x32 swizzle
// (inverse-swizzled global source + swizzled ds_read — rule #21), one barrier
// per K-tile, loads for tile t+1 issued before computing tile t.
template <int EPI, bool BIAS, bool LRELU>
__global__ __launch_bounds__(512, 2) void k_gemm256(
    const u16* __restrict__ A, const u16* __restrict__ B, void* __restrict__ C,
    const float* __restrict__ bias, int K, int N, float scale) {
  __shared__ u16 S[2][2][16384];   // [buf][opA/opB][256*64], 128 KiB total
  const int t = threadIdx.x;
  const int lane = t & 63;
  const int w = t >> 6;            // 0..7
  const int wr = w >> 2;           // 0..1  (M half)
  const int wc = w & 3;            // 0..3  (N quarter)
  const long row0 = (long)blockIdx.x * 256;
  const long col0 = (long)blockIdx.y * 256;
  const int nt = K >> 6;

  // staging: 4 chunks of 16B per operand per thread, pre-inverse-swizzled source
  const u16* pA[4];
  const u16* pB[4];
  int ldsoff[4];
#pragma unroll
  for (int i = 0; i < 4; ++i) {
    int d = t * 16 + i * 8192;                  // linear dest byte in tile
    int dx = d ^ (((d >> 9) & 1) << 5);         // involution source offset
    int srow = dx >> 7;
    int scol = (dx & 127) >> 1;
    ldsoff[i] = d >> 1;
    pA[i] = A + (row0 + srow) * (long)K + scol;
    pB[i] = B + (col0 + srow) * (long)K + scol;
  }

  // fragment read bases (swizzled)
  const int fr = lane & 15;
  const int fky = lane >> 4;                    // 0..3
  const int flip = (fr & 4) ? 32 : 0;
  const int aoff = (((wr * 128 + fr) * 128) + fky * 16) ^ flip;
  const int boff = (((wc * 64 + fr) * 128) + fky * 16) ^ flip;

  f32x4 acc[8][4] = {};

  auto STAGE = [&](int b) {
    u16* SA = &S[b][0][0];
    u16* SB = &S[b][1][0];
#pragma unroll
    for (int i = 0; i < 4; ++i) gld16(pA[i], SA + ldsoff[i]);
#pragma unroll
    for (int i = 0; i < 4; ++i) gld16(pB[i], SB + ldsoff[i]);
#pragma unroll
    for (int i = 0; i < 4; ++i) { pA[i] += 64; pB[i] += 64; }
  };

  auto COMPUTE = [&](int b) {
    const char* Ab = (const char*)&S[b][0][0] + aoff;
    const char* Bb = (const char*)&S[b][1][0] + boff;
    bf16x8 bv[8];
#pragma unroll
    for (int n = 0; n < 4; ++n)
#pragma unroll
      for (int kk = 0; kk < 2; ++kk)
        bv[n * 2 + kk] = *(const bf16x8*)(Bb + n * 2048 + kk * 64);
    __builtin_amdgcn_s_setprio(1);
#pragma unroll
    for (int m = 0; m < 8; ++m) {
      bf16x8 a0 = *(const bf16x8*)(Ab + m * 2048);
      bf16x8 a1 = *(const bf16x8*)(Ab + m * 2048 + 64);
#pragma unroll
      for (int n = 0; n < 4; ++n)
        acc[m][n] = __builtin_amdgcn_mfma_f32_16x16x32_bf16(a0, bv[n * 2], acc[m][n], 0, 0, 0);
#pragma unroll
      for (int n = 0; n < 4; ++n)
        acc[m][n] = __builtin_amdgcn_mfma_f32_16x16x32_bf16(a1, bv[n * 2 + 1], acc[m][n], 0, 0, 0);
    }
    __builtin_amdgcn_s_setprio(0);
  };

  STAGE(0);
  __syncthreads();                 // drain vmcnt(0) + barrier: buf0 ready
  int cur = 0;
  for (int tt = 0; tt < nt; ++tt) {
    if (tt + 1 < nt) STAGE(cur ^ 1);
    COMPUTE(cur);
    __syncthreads();               // waits my stage loads + all waves done reading cur
    cur ^= 1;
  }

  const int er = (lane >> 4) * 4;
  const int ec = lane & 15;
#pragma unroll
  for (int m = 0; m < 8; ++m) {
#pragma unroll
    for (int n = 0; n < 4; ++n) {
#pragma unroll
      for (int j = 0; j < 4; ++j) {
        long r = row0 + wr * 128 + m * 16 + er + j;
        long c = col0 + wc * 64 + n * 16 + ec;
        float v = acc[m][n][j] * scale;
        if (BIAS)  v += bias[c];
        if (LRELU) v = v > 0.f ? v : 0.01f * v;
        if (EPI == 0)      ((float*)C)[r * (long)N + c] = v;
        else if (EPI == 1) ((u16*)C)[r * (long)N + c] = f2b(v);
        else               ((float*)C)[r * (long)N + c] += v;
      }
    }
  }
}

extern "C" void kernel_launch(void* const* d_in, const int* in_sizes, int n_in,
                              void* d_out, int out_size, void* d_ws, size_t ws_size,
                              hipStream_t stream) {
  const int*   tokens = (const int*)d_in[0];
  const float* emb    = (const float*)d_in[1];
  const float* qk     = (const float*)d_in[2];
  const float* ov     = (const float*)d_in[3];
  const float* wup    = (const float*)d_in[4];
  const float* bup    = (const float*)d_in[5];
  const float* whid   = (const float*)d_in[6];
  const float* bhid   = (const float*)d_in[7];
  const float* wdown  = (const float*)d_in[8];
  const float* bdown  = (const float*)d_in[9];
  const float* g1     = (const float*)d_in[10];
  const float* b1     = (const float*)d_in[11];
  const float* g2     = (const float*)d_in[12];
  const float* b2     = (const float*)d_in[13];

  // scratch carved out of d_out (524 MB; only written by the final GEMM)
  char* Ob = (char*)d_out;
  float* scores = (float*)(Ob + 0);              // 33554432 B
  u16*   attn   = (u16*)(Ob + 33554432);         // 16777216 B
  u16*   m1     = (u16*)(Ob + 50331648);         // 33554432 B
  u16*   m2     = (u16*)(Ob + 83886080);         // 33554432 B
  u16*   qkT    = (u16*)(Ob + 117440512);        // 4 layers [1024][1024] bf16
  u16*   ovT    = (u16*)(Ob + 125829120);        // 4 layers
  u16*   upT    = (u16*)(Ob + 134217728);        // 4 layers [4096][1024]
  u16*   hidT   = (u16*)(Ob + 167772160);        // 4 layers [4096][4096]
  u16*   downT  = (u16*)(Ob + 301989888);        // 4 layers [1024][4096]
  float* xres   = (float*)(Ob + 335544320);      // residual f32 [4096][1024]
  u16*   h      = (u16*)(Ob + 352321536);        // LN out bf16
  u16*   hT     = (u16*)(Ob + 360710144);        // [2][1024][2048]
  u16*   q      = (u16*)(Ob + 369098752);        // [4096][1024]
  u16*   attnV  = (u16*)(Ob + 377487360);        // [4096][1024]

  // buffers live during the final GEMM go in d_ws
  u16* embB = (u16*)d_ws;                        // [32000][1024] bf16
  u16* xB   = (u16*)((char*)d_ws + 65536000);    // [4096][1024] bf16

  k_embed<<<dim3(BS), 256, 0, stream>>>(tokens, emb, xres);
  k_cvt<<<dim3(32000), 256, 0, stream>>>(emb, embB, 8192000);

  // all-layer batched weight transposes (z = layer)
  k_transpose<float><<<dim3(32, 32, 4),   256, 0, stream>>>(qk,    qkT,   1024, 1024, 1048576,  1048576);
  k_transpose<float><<<dim3(32, 32, 4),   256, 0, stream>>>(ov,    ovT,   1024, 1024, 1048576,  1048576);
  k_transpose<float><<<dim3(128, 32, 4),  256, 0, stream>>>(wup,   upT,   1024, 4096, 4194304,  4194304);
  k_transpose<float><<<dim3(128, 128, 4), 256, 0, stream>>>(whid,  hidT,  4096, 4096, 16777216, 16777216);
  k_transpose<float><<<dim3(32, 128, 4),  256, 0, stream>>>(wdown, downT, 4096, 1024, 4194304,  4194304);

  for (int l = 0; l < 4; ++l) {
    // ---- attention ----
    k_ln<<<dim3(BS), 256, 0, stream>>>(xres, g1 + l * 1024, b1 + l * 1024, h);
    k_transpose<u16><<<dim3(32, 64, 2), 256, 0, stream>>>(h, hT, 2048, 1024, 2048L * 1024, 1024L * 2048);
    // q = (h @ qk) / sqrt(d)
    k_gemm_bt<1, false, false, 0><<<dim3(32, 8, 1), 256, 0, stream>>>(
        h, qkT + (long)l * 1048576, q, nullptr, 1024, 1024, 0, 0, 0, 0.03125f);
    // scores[z] = q[z] @ h[z]^T (upper-triangle blocks skipped)
    k_gemm_bt<0, false, false, 1><<<dim3(16, 16, 2), 256, 0, stream>>>(
        q, h, scores, nullptr, 1024, 2048, 2048L * 1024, 2048L * 1024, 2048L * 2048, 1.f);
    k_softmax<<<dim3(2048, 2), 256, 0, stream>>>(scores, attn);
    // attnV[z] = attn[z] @ h[z] (K-loop causal-limited)
    k_gemm_bt<1, false, false, 2><<<dim3(16, 8, 2), 256, 0, stream>>>(
        attn, hT, attnV, nullptr, 2048, 1024, 2048L * 2048, 1024L * 2048, 2048L * 1024, 1.f);
    // x += attnV @ ov
    k_gemm_bt<2, false, false, 0><<<dim3(32, 8, 1), 256, 0, stream>>>(
        attnV, ovT + (long)l * 1048576, xres, nullptr, 1024, 1024, 0, 0, 0, 1.f);

    // ---- MLP ----
    k_ln<<<dim3(BS), 256, 0, stream>>>(xres, g2 + l * 1024, b2 + l * 1024, h);
    k_gemm256<1, true, true><<<dim3(16, 16), 512, 0, stream>>>(
        h, upT + (long)l * 4194304, m1, bup + l * 4096, 1024, 4096, 1.f);
    k_gemm256<1, true, true><<<dim3(16, 16), 512, 0, stream>>>(
        m1, hidT + (long)l * 16777216, m2, bhid + l * 4096, 4096, 4096, 1.f);
    k_gemm_bt<2, true, true, 0><<<dim3(32, 8, 1), 256, 0, stream>>>(
        m2, downT + (long)l * 4194304, xres, bdown + l * 1024, 4096, 1024, 0, 0, 0, 1.f);
  }

  // ---- logits = x @ emb^T ----
  k_cvt<<<dim3(4096), 256, 0, stream>>>(xres, xB, 1048576);
  k_gemm256<0, false, false><<<dim3(16, 125), 512, 0, stream>>>(
      xB, embB, (float*)d_out, nullptr, 1024, 32000, 1.f);
}

// Round 4
// 2120.201 us; speedup vs baseline: 1.1222x; 1.0093x over previous
//
#include <hip/hip_runtime.h>

#define BS   4096   // BATCH*SEQ
#define SEQL 2048
#define DM   1024
#define DH   4096
#define NV   32000

using u16 = unsigned short;

typedef __attribute__((ext_vector_type(8))) short bf16x8;
typedef __attribute__((ext_vector_type(4))) float f32x4;

__device__ __forceinline__ u16 f2b(float f) {
  union { float f; unsigned u; } c; c.f = f;
  unsigned u = c.u;
  u = (u + 0x7FFFu + ((u >> 16) & 1u)) >> 16;
  return (u16)u;
}

__device__ __forceinline__ void gld16(const u16* g, u16* l) {
  __builtin_amdgcn_global_load_lds(
      (__attribute__((address_space(1))) void*)(void*)const_cast<u16*>(g),
      (__attribute__((address_space(3))) void*)l, 16, 0, 0);
}

// ---------------- embed ----------------
__global__ __launch_bounds__(256) void k_embed(const int* __restrict__ tok,
                                               const float* __restrict__ emb,
                                               float* __restrict__ x) {
  const long row = blockIdx.x;
  const long e = tok[row];
  ((float4*)(x + row * DM))[threadIdx.x] = ((const float4*)(emb + e * DM))[threadIdx.x];
}

// ---------------- f32 -> bf16 convert ----------------
__global__ __launch_bounds__(256) void k_cvt(const float* __restrict__ in,
                                             u16* __restrict__ out, int n4) {
  int i = blockIdx.x * 256 + threadIdx.x;
  if (i < n4) {
    float4 v = ((const float4*)in)[i];
    ushort4 o;
    o.x = f2b(v.x); o.y = f2b(v.y); o.z = f2b(v.z); o.w = f2b(v.w);
    ((ushort4*)out)[i] = o;
  }
}

// ---------------- LayerNorm ----------------
__global__ __launch_bounds__(256) void k_ln(const float* __restrict__ x,
                                            const float* __restrict__ g,
                                            const float* __restrict__ b,
                                            u16* __restrict__ out) {
  const long row = blockIdx.x;
  const int t = threadIdx.x;
  float4 v = ((const float4*)(x + row * DM))[t];
  float s  = v.x + v.y + v.z + v.w;
  float q2 = v.x*v.x + v.y*v.y + v.z*v.z + v.w*v.w;
#pragma unroll
  for (int o = 1; o < 64; o <<= 1) { s += __shfl_xor(s, o); q2 += __shfl_xor(q2, o); }
  __shared__ float rs_[4], rq_[4];
  const int lane = t & 63, wid = t >> 6;
  if (lane == 0) { rs_[wid] = s; rq_[wid] = q2; }
  __syncthreads();
  s  = rs_[0] + rs_[1] + rs_[2] + rs_[3];
  q2 = rq_[0] + rq_[1] + rq_[2] + rq_[3];
  const float mu   = s * (1.f / 1024.f);
  const float var  = q2 * (1.f / 1024.f) - mu * mu;
  const float rstd = rsqrtf(var + 1e-5f);
  float4 gg = ((const float4*)g)[t];
  float4 bb = ((const float4*)b)[t];
  ushort4 o;
  o.x = f2b((v.x - mu) * rstd * gg.x + bb.x);
  o.y = f2b((v.y - mu) * rstd * gg.y + bb.y);
  o.z = f2b((v.z - mu) * rstd * gg.z + bb.z);
  o.w = f2b((v.w - mu) * rstd * gg.w + bb.w);
  ((ushort4*)(out + row * DM))[t] = o;
}

// ---------------- 32x32 tiled transpose ----------------
__device__ __forceinline__ u16 to_b16(float v) { return f2b(v); }
__device__ __forceinline__ u16 to_b16(u16 v)   { return v; }

template <typename T>
__global__ __launch_bounds__(256) void k_transpose(const T* __restrict__ in,
                                                   u16* __restrict__ out,
                                                   int R, int C, long inz, long outz) {
  __shared__ u16 tile[32][33];
  const T* ip = in + (long)blockIdx.z * inz;
  u16* op = out + (long)blockIdx.z * outz;
  const int tx = threadIdx.x & 31, ty = threadIdx.x >> 5;
  const long c0 = (long)blockIdx.x * 32, r0 = (long)blockIdx.y * 32;
#pragma unroll
  for (int i = 0; i < 4; ++i)
    tile[ty + i * 8][tx] = to_b16(ip[(r0 + ty + i * 8) * C + c0 + tx]);
  __syncthreads();
#pragma unroll
  for (int i = 0; i < 4; ++i)
    op[(c0 + ty + i * 8) * R + r0 + tx] = tile[tx][ty + i * 8];
}

// ---------------- causal row softmax ----------------
__global__ __launch_bounds__(256) void k_softmax(const float* __restrict__ sc,
                                                 u16* __restrict__ at) {
  const int r = blockIdx.x;
  const long z = blockIdx.y;
  const int t = threadIdx.x;
  const float* row = sc + (z * SEQL + r) * SEQL;
  u16* orow = at + (z * SEQL + r) * SEQL;
  float vals[8];
  float mx = -3.4e38f;
#pragma unroll
  for (int i = 0; i < 8; ++i) {
    int c = i * 256 + t;
    float v = (c <= r) ? row[c] : -3.4e38f;
    vals[i] = v;
    mx = fmaxf(mx, v);
  }
#pragma unroll
  for (int o = 1; o < 64; o <<= 1) mx = fmaxf(mx, __shfl_xor(mx, o));
  __shared__ float rm[4], rsum[4];
  const int lane = t & 63, wid = t >> 6;
  if (lane == 0) rm[wid] = mx;
  __syncthreads();
  mx = fmaxf(fmaxf(rm[0], rm[1]), fmaxf(rm[2], rm[3]));
  float sum = 0.f;
#pragma unroll
  for (int i = 0; i < 8; ++i) {
    int c = i * 256 + t;
    float e = (c <= r) ? __expf(vals[i] - mx) : 0.f;
    vals[i] = e;
    sum += e;
  }
#pragma unroll
  for (int o = 1; o < 64; o <<= 1) sum += __shfl_xor(sum, o);
  if (lane == 0) rsum[wid] = sum;
  __syncthreads();
  sum = rsum[0] + rsum[1] + rsum[2] + rsum[3];
  const float inv = 1.f / sum;
#pragma unroll
  for (int i = 0; i < 8; ++i) orow[i * 256 + t] = f2b(vals[i] * inv);
}

// ---------------- 128x128 bf16 GEMM (small/causal shapes) ----------------
template <int EPI, bool BIAS, bool LRELU, int CAUSAL>
__global__ __launch_bounds__(256, 2) void k_gemm_bt(
    const u16* __restrict__ A, const u16* __restrict__ B, void* __restrict__ C,
    const float* __restrict__ bias, int K, int N,
    long sAz, long sBz, long sCz, float scale) {
  __shared__ u16 lA[128 * 32];
  __shared__ u16 lB[128 * 32];
  const int t = threadIdx.x;
  const long z = blockIdx.z;
  const long row0 = (long)blockIdx.x * 128;
  const long col0 = (long)blockIdx.y * 128;
  if (CAUSAL == 1 && col0 > row0 + 127) return;
  const int Klim = (CAUSAL == 2) ? min(K, (int)row0 + 128) : K;
  const u16* Ab = A + z * sAz;
  const u16* Bb = B + z * sBz;

  const int rr = t >> 2;
  const int c8 = (t & 3) * 8;
  const u16* gA0 = Ab + (row0 + rr) * K + c8;
  const u16* gA1 = Ab + (row0 + 64 + rr) * K + c8;
  const u16* gB0 = Bb + (col0 + rr) * K + c8;
  const u16* gB1 = Bb + (col0 + 64 + rr) * K + c8;
  u16* sA0 = &lA[rr * 32 + c8];
  u16* sA1 = &lA[(64 + rr) * 32 + c8];
  u16* sB0 = &lB[rr * 32 + c8];
  u16* sB1 = &lB[(64 + rr) * 32 + c8];

  const int lane = t & 63;
  const int w = t >> 6;
  const int wr = (w >> 1) * 64, wc = (w & 1) * 64;
  const int fr = lane & 15;
  const int fk = (lane >> 4) * 8;

  f32x4 acc[4][4] = {};

  for (int k0 = 0; k0 < Klim; k0 += 32) {
    gld16(gA0 + k0, sA0);
    gld16(gA1 + k0, sA1);
    gld16(gB0 + k0, sB0);
    gld16(gB1 + k0, sB1);
    __syncthreads();
    bf16x8 av[4], bv[4];
#pragma unroll
    for (int m = 0; m < 4; ++m) av[m] = *(const bf16x8*)&lA[(wr + m * 16 + fr) * 32 + fk];
#pragma unroll
    for (int n = 0; n < 4; ++n) bv[n] = *(const bf16x8*)&lB[(wc + n * 16 + fr) * 32 + fk];
#pragma unroll
    for (int m = 0; m < 4; ++m)
#pragma unroll
      for (int n = 0; n < 4; ++n)
        acc[m][n] = __builtin_amdgcn_mfma_f32_16x16x32_bf16(av[m], bv[n], acc[m][n], 0, 0, 0);
    __syncthreads();
  }

  const int er = (lane >> 4) * 4;
  const int ec = lane & 15;
#pragma unroll
  for (int m = 0; m < 4; ++m) {
#pragma unroll
    for (int n = 0; n < 4; ++n) {
#pragma unroll
      for (int j = 0; j < 4; ++j) {
        long r = row0 + wr + m * 16 + er + j;
        long c = col0 + wc + n * 16 + ec;
        float v = acc[m][n][j] * scale;
        if (BIAS)  v += bias[c];
        if (LRELU) v = v > 0.f ? v : 0.01f * v;
        if (EPI == 0)      ((float*)C)[z * sCz + r * (long)N + c] = v;
        else if (EPI == 1) ((u16*)C)[z * sCz + r * (long)N + c] = f2b(v);
        else               ((float*)C)[z * sCz + r * (long)N + c] += v;
      }
    }
  }
}

// ---------------- 256x256 BK=64 8-wave bf16 GEMM (large shapes) ----------------
// C[M,N] = A[M,K] @ B[N,K]^T.  Double-buffered 128KB LDS.
// Swizzle: byte ^= ((row&7)<<4) (G4 recipe, matched to "16 lanes / 16 rows /
// fixed 16B col" read pattern: slot = fky ^ (fr&7) spreads uniformly over all
// 32 banks). Involution on bits 4-6 keyed by row bits 0-2; applied BOTH sides
// (inverse-swizzled global source + swizzled ds_read) per rule #21.
template <int EPI, bool BIAS, bool LRELU>
__global__ __launch_bounds__(512, 2) void k_gemm256(
    const u16* __restrict__ A, const u16* __restrict__ B, void* __restrict__ C,
    const float* __restrict__ bias, int K, int N, float scale) {
  __shared__ u16 S[2][2][16384];   // [buf][opA/opB][256*64], 128 KiB total
  const int t = threadIdx.x;
  const int lane = t & 63;
  const int w = t >> 6;            // 0..7
  const int wr = w >> 2;           // 0..1  (M half)
  const int wc = w & 3;            // 0..3  (N quarter)
  const long row0 = (long)blockIdx.x * 256;
  const long col0 = (long)blockIdx.y * 256;
  const int nt = K >> 6;

  // staging: linear LDS dest, inverse-swizzled global source
  const u16* pA[4];
  const u16* pB[4];
  int ldsoff[4];
#pragma unroll
  for (int i = 0; i < 4; ++i) {
    int d = t * 16 + i * 8192;                  // linear dest byte in tile
    int dx = d ^ (((d >> 7) & 7) << 4);         // involution -> source position
    int srow = dx >> 7;
    int scol = (dx & 127) >> 1;
    ldsoff[i] = d >> 1;
    pA[i] = A + (row0 + srow) * (long)K + scol;
    pB[i] = B + (col0 + srow) * (long)K + scol;
  }

  // fragment read bases (swizzled): row&7 == fr&7 for all m/n/kk terms
  const int fr = lane & 15;
  const int fky = lane >> 4;                    // 0..3
  const int axor = (fr & 7) << 4;
  const int abase = (wr * 128 + fr) * 128 + fky * 16;
  const int bbase = (wc * 64 + fr) * 128 + fky * 16;

  f32x4 acc[8][4] = {};

  auto STAGE = [&](int b) {
    u16* SA = &S[b][0][0];
    u16* SB = &S[b][1][0];
#pragma unroll
    for (int i = 0; i < 4; ++i) gld16(pA[i], SA + ldsoff[i]);
#pragma unroll
    for (int i = 0; i < 4; ++i) gld16(pB[i], SB + ldsoff[i]);
#pragma unroll
    for (int i = 0; i < 4; ++i) { pA[i] += 64; pB[i] += 64; }
  };

  auto COMPUTE = [&](int b) {
    const char* Ab = (const char*)&S[b][0][0];
    const char* Bb = (const char*)&S[b][1][0];
    bf16x8 bv[8];
#pragma unroll
    for (int n = 0; n < 4; ++n)
#pragma unroll
      for (int kk = 0; kk < 2; ++kk)
        bv[n * 2 + kk] = *(const bf16x8*)(Bb + ((bbase + n * 2048 + kk * 64) ^ axor));
    __builtin_amdgcn_s_setprio(1);
#pragma unroll
    for (int m = 0; m < 8; ++m) {
      bf16x8 a0 = *(const bf16x8*)(Ab + ((abase + m * 2048) ^ axor));
      bf16x8 a1 = *(const bf16x8*)(Ab + ((abase + m * 2048 + 64) ^ axor));
#pragma unroll
      for (int n = 0; n < 4; ++n)
        acc[m][n] = __builtin_amdgcn_mfma_f32_16x16x32_bf16(a0, bv[n * 2], acc[m][n], 0, 0, 0);
#pragma unroll
      for (int n = 0; n < 4; ++n)
        acc[m][n] = __builtin_amdgcn_mfma_f32_16x16x32_bf16(a1, bv[n * 2 + 1], acc[m][n], 0, 0, 0);
    }
    __builtin_amdgcn_s_setprio(0);
  };

  STAGE(0);
  __syncthreads();                 // buf0 ready
  int cur = 0;
  for (int tt = 0; tt < nt; ++tt) {
    if (tt + 1 < nt) STAGE(cur ^ 1);
    COMPUTE(cur);
    __syncthreads();
    cur ^= 1;
  }

  const int er = (lane >> 4) * 4;
  const int ec = lane & 15;
#pragma unroll
  for (int m = 0; m < 8; ++m) {
#pragma unroll
    for (int n = 0; n < 4; ++n) {
#pragma unroll
      for (int j = 0; j < 4; ++j) {
        long r = row0 + wr * 128 + m * 16 + er + j;
        long c = col0 + wc * 64 + n * 16 + ec;
        float v = acc[m][n][j] * scale;
        if (BIAS)  v += bias[c];
        if (LRELU) v = v > 0.f ? v : 0.01f * v;
        if (EPI == 0)      ((float*)C)[r * (long)N + c] = v;
        else if (EPI == 1) ((u16*)C)[r * (long)N + c] = f2b(v);
        else               ((float*)C)[r * (long)N + c] += v;
      }
    }
  }
}

extern "C" void kernel_launch(void* const* d_in, const int* in_sizes, int n_in,
                              void* d_out, int out_size, void* d_ws, size_t ws_size,
                              hipStream_t stream) {
  const int*   tokens = (const int*)d_in[0];
  const float* emb    = (const float*)d_in[1];
  const float* qk     = (const float*)d_in[2];
  const float* ov     = (const float*)d_in[3];
  const float* wup    = (const float*)d_in[4];
  const float* bup    = (const float*)d_in[5];
  const float* whid   = (const float*)d_in[6];
  const float* bhid   = (const float*)d_in[7];
  const float* wdown  = (const float*)d_in[8];
  const float* bdown  = (const float*)d_in[9];
  const float* g1     = (const float*)d_in[10];
  const float* b1     = (const float*)d_in[11];
  const float* g2     = (const float*)d_in[12];
  const float* b2     = (const float*)d_in[13];

  // scratch carved out of d_out (524 MB; only written by the final GEMM)
  char* Ob = (char*)d_out;
  float* scores = (float*)(Ob + 0);              // 33554432 B
  u16*   attn   = (u16*)(Ob + 33554432);         // 16777216 B
  u16*   m1     = (u16*)(Ob + 50331648);         // 33554432 B
  u16*   m2     = (u16*)(Ob + 83886080);         // 33554432 B
  u16*   qkT    = (u16*)(Ob + 117440512);        // 4 layers [1024][1024] bf16
  u16*   ovT    = (u16*)(Ob + 125829120);        // 4 layers
  u16*   upT    = (u16*)(Ob + 134217728);        // 4 layers [4096][1024]
  u16*   hidT   = (u16*)(Ob + 167772160);        // 4 layers [4096][4096]
  u16*   downT  = (u16*)(Ob + 301989888);        // 4 layers [1024][4096]
  float* xres   = (float*)(Ob + 335544320);      // residual f32 [4096][1024]
  u16*   h      = (u16*)(Ob + 352321536);        // LN out bf16
  u16*   hT     = (u16*)(Ob + 360710144);        // [2][1024][2048]
  u16*   q      = (u16*)(Ob + 369098752);        // [4096][1024]
  u16*   attnV  = (u16*)(Ob + 377487360);        // [4096][1024]

  // buffers live during the final GEMM go in d_ws
  u16* embB = (u16*)d_ws;                        // [32000][1024] bf16
  u16* xB   = (u16*)((char*)d_ws + 65536000);    // [4096][1024] bf16

  k_embed<<<dim3(BS), 256, 0, stream>>>(tokens, emb, xres);
  k_cvt<<<dim3(32000), 256, 0, stream>>>(emb, embB, 8192000);

  // all-layer batched weight transposes (z = layer)
  k_transpose<float><<<dim3(32, 32, 4),   256, 0, stream>>>(qk,    qkT,   1024, 1024, 1048576,  1048576);
  k_transpose<float><<<dim3(32, 32, 4),   256, 0, stream>>>(ov,    ovT,   1024, 1024, 1048576,  1048576);
  k_transpose<float><<<dim3(128, 32, 4),  256, 0, stream>>>(wup,   upT,   1024, 4096, 4194304,  4194304);
  k_transpose<float><<<dim3(128, 128, 4), 256, 0, stream>>>(whid,  hidT,  4096, 4096, 16777216, 16777216);
  k_transpose<float><<<dim3(32, 128, 4),  256, 0, stream>>>(wdown, downT, 4096, 1024, 4194304,  4194304);

  for (int l = 0; l < 4; ++l) {
    // ---- attention ----
    k_ln<<<dim3(BS), 256, 0, stream>>>(xres, g1 + l * 1024, b1 + l * 1024, h);
    k_transpose<u16><<<dim3(32, 64, 2), 256, 0, stream>>>(h, hT, 2048, 1024, 2048L * 1024, 1024L * 2048);
    // q = (h @ qk) / sqrt(d)
    k_gemm_bt<1, false, false, 0><<<dim3(32, 8, 1), 256, 0, stream>>>(
        h, qkT + (long)l * 1048576, q, nullptr, 1024, 1024, 0, 0, 0, 0.03125f);
    // scores[z] = q[z] @ h[z]^T (upper-triangle blocks skipped)
    k_gemm_bt<0, false, false, 1><<<dim3(16, 16, 2), 256, 0, stream>>>(
        q, h, scores, nullptr, 1024, 2048, 2048L * 1024, 2048L * 1024, 2048L * 2048, 1.f);
    k_softmax<<<dim3(2048, 2), 256, 0, stream>>>(scores, attn);
    // attnV[z] = attn[z] @ h[z] (K-loop causal-limited)
    k_gemm_bt<1, false, false, 2><<<dim3(16, 8, 2), 256, 0, stream>>>(
        attn, hT, attnV, nullptr, 2048, 1024, 2048L * 2048, 1024L * 2048, 2048L * 1024, 1.f);
    // x += attnV @ ov
    k_gemm_bt<2, false, false, 0><<<dim3(32, 8, 1), 256, 0, stream>>>(
        attnV, ovT + (long)l * 1048576, xres, nullptr, 1024, 1024, 0, 0, 0, 1.f);

    // ---- MLP ----
    k_ln<<<dim3(BS), 256, 0, stream>>>(xres, g2 + l * 1024, b2 + l * 1024, h);
    k_gemm256<1, true, true><<<dim3(16, 16), 512, 0, stream>>>(
        h, upT + (long)l * 4194304, m1, bup + l * 4096, 1024, 4096, 1.f);
    k_gemm256<1, true, true><<<dim3(16, 16), 512, 0, stream>>>(
        m1, hidT + (long)l * 16777216, m2, bhid + l * 4096, 4096, 4096, 1.f);
    k_gemm_bt<2, true, true, 0><<<dim3(32, 8, 1), 256, 0, stream>>>(
        m2, downT + (long)l * 4194304, xres, bdown + l * 1024, 4096, 1024, 0, 0, 0, 1.f);
  }

  // ---- logits = x @ emb^T ----
  k_cvt<<<dim3(4096), 256, 0, stream>>>(xres, xB, 1048576);
  k_gemm256<0, false, false><<<dim3(16, 125), 512, 0, stream>>>(
      xB, embB, (float*)d_out, nullptr, 1024, 32000, 1.f);
}